// Round 6
// baseline (263.516 us; speedup 1.0000x reference)
//
#include <hip/hip_runtime.h>
#include <math.h>

#define NROWS 32768
#define DDIM 256
#define KCODES 1024

constexpr int BM = 64;     // rows per block (GEMM)
constexpr int BN = 128;    // codes per block (GEMM)
constexpr int DK = 32;     // d-chunk staged in LDS
constexpr int KSPLIT = 8;  // code-dimension split across blocks

// ---- x2[n] = np.sum(x*x, axis=1) emulating numpy pairwise_sum (AVX512) -----
// n=256 -> pairwise(0:128) + pairwise(128:256). Each 128-block (SIMD path,
// nlanes=16): 8 vector accs r0..r7 = loads of elems [16v,16v+16), no loop
// iters, combine ((r0+r1)+(r2+r3))+((r4+r5)+(r6+r7)), then npyv_sum lane
// tree (p,p+8),(p,p+4),(p,p+2),(p,p+1). Leaves are fl(x*x), all ops fp32.
constexpr int X2ROWS = 32;
__global__ __launch_bounds__(256) void vq_x2(const float* __restrict__ x,
                                             float* __restrict__ x2) {
    __shared__ float lds[X2ROWS][257];
    const int rb = blockIdx.x;  // 1024 blocks x 32 rows
    const int tid = threadIdx.x;
    const float4* src =
        reinterpret_cast<const float4*>(x + (size_t)rb * X2ROWS * DDIM);
#pragma unroll
    for (int i = 0; i < 8; ++i) {
        int e4 = tid + i * 256;  // 2048 float4 per block
        int row = e4 >> 6;       // 64 float4 per row
        int col = e4 & 63;
        float4 v = src[e4];
        lds[row][col * 4 + 0] = v.x;
        lds[row][col * 4 + 1] = v.y;
        lds[row][col * 4 + 2] = v.z;
        lds[row][col * 4 + 3] = v.w;
    }
    __syncthreads();
    if (tid < X2ROWS) {
        const float* r = lds[tid];
        float halves[2];
#pragma unroll
        for (int h = 0; h < 2; ++h) {
            const float* b = r + h * 128;
            float L[16];
#pragma unroll
            for (int p = 0; p < 16; ++p) {
                float t0 = __fmul_rn(b[p], b[p]);
                float t1 = __fmul_rn(b[16 + p], b[16 + p]);
                float t2 = __fmul_rn(b[32 + p], b[32 + p]);
                float t3 = __fmul_rn(b[48 + p], b[48 + p]);
                float t4 = __fmul_rn(b[64 + p], b[64 + p]);
                float t5 = __fmul_rn(b[80 + p], b[80 + p]);
                float t6 = __fmul_rn(b[96 + p], b[96 + p]);
                float t7 = __fmul_rn(b[112 + p], b[112 + p]);
                L[p] = __fadd_rn(
                    __fadd_rn(__fadd_rn(t0, t1), __fadd_rn(t2, t3)),
                    __fadd_rn(__fadd_rn(t4, t5), __fadd_rn(t6, t7)));
            }
            float s1[8];
#pragma unroll
            for (int p = 0; p < 8; ++p) s1[p] = __fadd_rn(L[p], L[p + 8]);
            float s2[4];
#pragma unroll
            for (int p = 0; p < 4; ++p) s2[p] = __fadd_rn(s1[p], s1[p + 4]);
            float s30 = __fadd_rn(s2[0], s2[2]);
            float s31 = __fadd_rn(s2[1], s2[3]);
            halves[h] = __fadd_rn(s30, s31);
        }
        x2[(size_t)rb * X2ROWS + tid] = __fadd_rn(halves[0], halves[1]);
    }
}

// ---- e2[k] = np.sum(e*e, axis=0): axis-0 reduce = sequential over d, -------
// separate mul (temp array) then add, both fp32-rounded. No pairwise.
__global__ __launch_bounds__(256) void vq_e2(const float* __restrict__ e,
                                             float* __restrict__ e2) {
    int k = blockIdx.x * 256 + threadIdx.x;  // 4 blocks
    float v0 = e[k];
    float s = __fmul_rn(v0, v0);
    for (int d = 1; d < DDIM; ++d) {
        float v = e[d * KCODES + k];
        s = __fadd_rn(s, __fmul_rn(v, v));
    }
    e2[k] = s;
}

// ---------------- transpose E [256,1024] -> ET [1024,256] (exact copy) ------
__global__ __launch_bounds__(256) void vq_transpose(const float* __restrict__ e,
                                                    float* __restrict__ et) {
    __shared__ float tile[32][33];
    int bk = blockIdx.x;  // 32 k-tiles
    int bd = blockIdx.y;  // 8 d-tiles
    int tx = threadIdx.x & 31;
    int ty = threadIdx.x >> 5;  // 0..7
#pragma unroll
    for (int p = 0; p < 4; ++p)
        tile[ty + p * 8][tx] = e[(bd * 32 + ty + p * 8) * KCODES + bk * 32 + tx];
    __syncthreads();
#pragma unroll
    for (int p = 0; p < 4; ++p)
        et[(bk * 32 + ty + p * 8) * DDIM + bd * 32 + tx] = tile[tx][ty + p * 8];
}

// ---- main: in-order-k single-acc fma GEMM (== sgemm microkernel order) -----
// + np-exact dist and first-min argmin partials
__global__ __launch_bounds__(256) void vq_argmin_partial(
    const float* __restrict__ x, const float* __restrict__ e,
    const float* __restrict__ x2g, const float* __restrict__ e2g,
    float* __restrict__ pdist, int* __restrict__ pidx) {
    __shared__ float As[DK][BM];
    __shared__ float Bs[DK][BN];

    const int rb = blockIdx.x;  // 0..511
    const int ks = blockIdx.y;  // 0..KSPLIT-1
    const int row0 = rb * BM;
    const int c0 = ks * BN;
    const int tid = threadIdx.x;
    const int tx = tid & 15;  // code group (8 codes)
    const int ty = tid >> 4;  // row group (4 rows)

    float acc[4][8];
#pragma unroll
    for (int i = 0; i < 4; ++i)
#pragma unroll
        for (int j = 0; j < 8; ++j) acc[i][j] = 0.f;

    for (int d0 = 0; d0 < DDIM; d0 += DK) {
        {
            int g = tid & 7;
            int r = tid >> 3;
#pragma unroll
            for (int p = 0; p < 2; ++p) {
                int row = r + p * 32;
                const float4 v = *reinterpret_cast<const float4*>(
                    &x[(size_t)(row0 + row) * DDIM + d0 + g * 4]);
                As[g * 4 + 0][row] = v.x;
                As[g * 4 + 1][row] = v.y;
                As[g * 4 + 2][row] = v.z;
                As[g * 4 + 3][row] = v.w;
            }
        }
        {
            int c4 = tid & 31;
            int dd0 = tid >> 5;
#pragma unroll
            for (int p = 0; p < 4; ++p) {
                int dd = dd0 + p * 8;
                const float4 v = *reinterpret_cast<const float4*>(
                    &e[(size_t)(d0 + dd) * KCODES + c0 + c4 * 4]);
                *reinterpret_cast<float4*>(&Bs[dd][c4 * 4]) = v;
            }
        }
        __syncthreads();
#pragma unroll
        for (int dd = 0; dd < DK; ++dd) {
            float4 a = *reinterpret_cast<const float4*>(&As[dd][ty * 4]);
            float4 b0 = *reinterpret_cast<const float4*>(&Bs[dd][tx * 8]);
            float4 b1 = *reinterpret_cast<const float4*>(&Bs[dd][tx * 8 + 4]);
            float av[4] = {a.x, a.y, a.z, a.w};
            float bv[8] = {b0.x, b0.y, b0.z, b0.w, b1.x, b1.y, b1.z, b1.w};
#pragma unroll
            for (int i = 0; i < 4; ++i)
#pragma unroll
                for (int j = 0; j < 8; ++j)
                    acc[i][j] = fmaf(av[i], bv[j], acc[i][j]);
        }
        __syncthreads();
    }

    // np dist: fl(fl(x2 + e2) - fl(2*sim)); argmin = first-min, k ascending
    float xr[4];
#pragma unroll
    for (int i = 0; i < 4; ++i) xr[i] = x2g[row0 + ty * 4 + i];

    float best[4];
    int bidx[4];
#pragma unroll
    for (int i = 0; i < 4; ++i) {
        best[i] = INFINITY;
        bidx[i] = 0x7fffffff;
    }
#pragma unroll
    for (int j = 0; j < 8; ++j) {
        int k = c0 + tx * 8 + j;
        float ek = e2g[k];
#pragma unroll
        for (int i = 0; i < 4; ++i) {
            float u = __fadd_rn(xr[i], ek);
            float dct = __fsub_rn(u, __fmul_rn(2.0f, acc[i][j]));
            if (dct < best[i]) {  // strict <, j ascending => first-min
                best[i] = dct;
                bidx[i] = k;
            }
        }
    }
#pragma unroll
    for (int m = 1; m < 16; m <<= 1) {
#pragma unroll
        for (int i = 0; i < 4; ++i) {
            float od = __shfl_xor(best[i], m);
            int oi = __shfl_xor(bidx[i], m);
            if (od < best[i] || (od == best[i] && oi < bidx[i])) {
                best[i] = od;
                bidx[i] = oi;
            }
        }
    }
    if (tx == 0) {
#pragma unroll
        for (int i = 0; i < 4; ++i) {
            int row = row0 + ty * 4 + i;
            pdist[(size_t)ks * NROWS + row] = best[i];
            pidx[(size_t)ks * NROWS + row] = bidx[i];
        }
    }
}

// ------------- pick: merge splits (ks ascending == k ascending) -------------
__global__ __launch_bounds__(256) void vq_pick(const float* __restrict__ pdist,
                                               const int* __restrict__ pidx,
                                               int* __restrict__ idx) {
    int row = blockIdx.x * 256 + threadIdx.x;  // 128 blocks
    float gb = INFINITY;
    int gi = 0;
#pragma unroll
    for (int s = 0; s < KSPLIT; ++s) {
        float d = pdist[(size_t)s * NROWS + row];
        int k = pidx[(size_t)s * NROWS + row];
        if (d < gb) {  // strict <: earlier split (lower k) wins ties
            gb = d;
            gi = k;
        }
    }
    idx[row] = gi;
}

// ------------- output: gather + fp32 STE out + per-block loss partial -------
__global__ __launch_bounds__(256) void vq_output(
    const float* __restrict__ x, const float* __restrict__ et,
    const int* __restrict__ idx, float* __restrict__ out,
    float* __restrict__ blockloss) {
    __shared__ int skb[64];
    __shared__ float red[256];
    const int rb = blockIdx.x;  // 512 blocks x 64 rows
    const int tid = threadIdx.x;
    if (tid < 64) skb[tid] = idx[rb * 64 + tid];
    __syncthreads();
    float lsum = 0.f;
    for (int r = 0; r < 64; ++r) {
        int row = rb * 64 + r;
        int k = skb[r];
        float xv = x[(size_t)row * DDIM + tid];
        float qv = et[(size_t)k * DDIM + tid];
        float diff = __fsub_rn(qv, xv);   // fl(q - x)
        float qst = __fadd_rn(xv, diff);  // fl(x + fl(q - x))
        out[(size_t)row * DDIM + tid] = qst;  // fp32 write
        lsum = fmaf(diff, diff, lsum);
    }
    red[tid] = lsum;
    __syncthreads();
    for (int s = 128; s > 0; s >>= 1) {
        if (tid < s) red[tid] += red[tid + s];
        __syncthreads();
    }
    if (tid == 0) blockloss[rb] = red[0];
}

// ---------------- deterministic loss reduce (fp32 scalar out) ---------------
__global__ __launch_bounds__(512) void vq_loss_reduce(
    const float* __restrict__ blockloss, float* __restrict__ out_loss) {
    __shared__ float red[512];
    int tid = threadIdx.x;
    red[tid] = blockloss[tid];
    __syncthreads();
    for (int s = 256; s > 0; s >>= 1) {
        if (tid < s) red[tid] += red[tid + s];
        __syncthreads();
    }
    if (tid == 0) {
        // np: loss = fl(fl(0.25*m) + m), m = sum/N, N = 2^23 (exact divide)
        float m = __fmul_rn(red[0], 1.0f / (float)((size_t)NROWS * DDIM));
        out_loss[0] = __fadd_rn(__fmul_rn(0.25f, m), m);
    }
}

extern "C" void kernel_launch(void* const* d_in, const int* in_sizes, int n_in,
                              void* d_out, int out_size, void* d_ws,
                              size_t ws_size, hipStream_t stream) {
    const float* x = (const float*)d_in[0];  // [32768, 256] fp32
    const float* e = (const float*)d_in[1];  // [256, 1024]  fp32
    float* out = (float*)d_out;              // 8388608 qst + 1 loss, all fp32

    float* ws = (float*)d_ws;
    float* x2 = ws;                                     // 32768
    float* e2 = x2 + NROWS;                             // 1024
    float* et = e2 + KCODES;                            // 262144
    float* pdist = et + (size_t)KCODES * DDIM;          // 8*32768
    int* pidx = (int*)(pdist + (size_t)KSPLIT * NROWS); // 8*32768
    int* idx = pidx + (size_t)KSPLIT * NROWS;           // 32768
    float* blockloss = (float*)(idx + NROWS);           // 512

    vq_x2<<<NROWS / X2ROWS, 256, 0, stream>>>(x, x2);
    vq_e2<<<KCODES / 256, 256, 0, stream>>>(e, e2);
    vq_transpose<<<dim3(32, 8), 256, 0, stream>>>(e, et);
    vq_argmin_partial<<<dim3(NROWS / BM, KSPLIT), 256, 0, stream>>>(
        x, e, x2, e2, pdist, pidx);
    vq_pick<<<NROWS / 256, 256, 0, stream>>>(pdist, pidx, idx);
    vq_output<<<NROWS / 64, 256, 0, stream>>>(x, et, idx, out, blockloss);
    vq_loss_reduce<<<1, 512, 0, stream>>>(blockloss, out + (size_t)NROWS * DDIM);
}

// Round 7
// 238.244 us; speedup vs baseline: 1.1061x; 1.1061x over previous
//
#include <hip/hip_runtime.h>
#include <math.h>

#define NROWS 32768
#define DDIM 256
#define KCODES 1024

constexpr int BM = 128;    // rows per block (GEMM)
constexpr int BN = 128;    // codes per block (GEMM)
constexpr int DK = 32;     // d-chunk staged in LDS
constexpr int KSPLIT = 8;  // code-dimension split across blocks

typedef float v2f __attribute__((ext_vector_type(2)));

// ---- x2[n] = np.sum(x*x, axis=1) emulating numpy pairwise_sum (AVX512) -----
// (verified bit-exact in R6 — do not change)
constexpr int X2ROWS = 32;
__global__ __launch_bounds__(256) void vq_x2(const float* __restrict__ x,
                                             float* __restrict__ x2) {
    __shared__ float lds[X2ROWS][257];
    const int rb = blockIdx.x;  // 1024 blocks x 32 rows
    const int tid = threadIdx.x;
    const float4* src =
        reinterpret_cast<const float4*>(x + (size_t)rb * X2ROWS * DDIM);
#pragma unroll
    for (int i = 0; i < 8; ++i) {
        int e4 = tid + i * 256;
        int row = e4 >> 6;
        int col = e4 & 63;
        float4 v = src[e4];
        lds[row][col * 4 + 0] = v.x;
        lds[row][col * 4 + 1] = v.y;
        lds[row][col * 4 + 2] = v.z;
        lds[row][col * 4 + 3] = v.w;
    }
    __syncthreads();
    if (tid < X2ROWS) {
        const float* r = lds[tid];
        float halves[2];
#pragma unroll
        for (int h = 0; h < 2; ++h) {
            const float* b = r + h * 128;
            float L[16];
#pragma unroll
            for (int p = 0; p < 16; ++p) {
                float t0 = __fmul_rn(b[p], b[p]);
                float t1 = __fmul_rn(b[16 + p], b[16 + p]);
                float t2 = __fmul_rn(b[32 + p], b[32 + p]);
                float t3 = __fmul_rn(b[48 + p], b[48 + p]);
                float t4 = __fmul_rn(b[64 + p], b[64 + p]);
                float t5 = __fmul_rn(b[80 + p], b[80 + p]);
                float t6 = __fmul_rn(b[96 + p], b[96 + p]);
                float t7 = __fmul_rn(b[112 + p], b[112 + p]);
                L[p] = __fadd_rn(
                    __fadd_rn(__fadd_rn(t0, t1), __fadd_rn(t2, t3)),
                    __fadd_rn(__fadd_rn(t4, t5), __fadd_rn(t6, t7)));
            }
            float s1[8];
#pragma unroll
            for (int p = 0; p < 8; ++p) s1[p] = __fadd_rn(L[p], L[p + 8]);
            float s2[4];
#pragma unroll
            for (int p = 0; p < 4; ++p) s2[p] = __fadd_rn(s1[p], s1[p + 4]);
            float s30 = __fadd_rn(s2[0], s2[2]);
            float s31 = __fadd_rn(s2[1], s2[3]);
            halves[h] = __fadd_rn(s30, s31);
        }
        x2[(size_t)rb * X2ROWS + tid] = __fadd_rn(halves[0], halves[1]);
    }
}

// ---- e2[k] = np.sum(e*e, axis=0): sequential over d (verified) -------------
__global__ __launch_bounds__(256) void vq_e2(const float* __restrict__ e,
                                             float* __restrict__ e2) {
    int k = blockIdx.x * 256 + threadIdx.x;
    float v0 = e[k];
    float s = __fmul_rn(v0, v0);
    for (int d = 1; d < DDIM; ++d) {
        float v = e[d * KCODES + k];
        s = __fadd_rn(s, __fmul_rn(v, v));
    }
    e2[k] = s;
}

// ---------------- transpose E [256,1024] -> ET [1024,256] -------------------
__global__ __launch_bounds__(256) void vq_transpose(const float* __restrict__ e,
                                                    float* __restrict__ et) {
    __shared__ float tile[32][33];
    int bk = blockIdx.x;
    int bd = blockIdx.y;
    int tx = threadIdx.x & 31;
    int ty = threadIdx.x >> 5;
#pragma unroll
    for (int p = 0; p < 4; ++p)
        tile[ty + p * 8][tx] = e[(bd * 32 + ty + p * 8) * KCODES + bk * 32 + tx];
    __syncthreads();
#pragma unroll
    for (int p = 0; p < 4; ++p)
        et[(bk * 32 + ty + p * 8) * DDIM + bd * 32 + tx] = tile[tx][ty + p * 8];
}

// ---- main: in-order-k fma GEMM, 128x128 tile, 8x8/thread, packed fp32 ------
__global__ __launch_bounds__(256) void vq_argmin_partial(
    const float* __restrict__ x, const float* __restrict__ e,
    const float* __restrict__ x2g, const float* __restrict__ e2g,
    float* __restrict__ pdist, int* __restrict__ pidx) {
    __shared__ float As[BM][33];  // row-major + pad: conflict-free scalar r/w
    __shared__ float Bs[DK][BN];

    const int rb = blockIdx.x;  // 0..255
    const int ks = blockIdx.y;  // 0..7
    const int row0 = rb * BM;
    const int c0 = ks * BN;
    const int tid = threadIdx.x;
    const int tx = tid & 15;  // code group: {tx*4..+3} and {64+tx*4..+3}
    const int ty = tid >> 4;  // row group: rows ty*8..ty*8+7

    // acc2[i][jp]: row ty*8+i; jp<2 -> codes tx*4+2jp+{0,1};
    //              jp>=2 -> codes 64+tx*4+2(jp-2)+{0,1}
    v2f acc2[8][4];
#pragma unroll
    for (int i = 0; i < 8; ++i)
#pragma unroll
        for (int jp = 0; jp < 4; ++jp) acc2[i][jp] = (v2f)(0.f);

    for (int d0 = 0; d0 < DDIM; d0 += DK) {
        // A tile: 128 rows x 32 d. float4 global load, scalar LDS writes.
        {
            int g = tid & 7;           // which float4 within the d-chunk
            int r0t = tid >> 3;        // 0..31
#pragma unroll
            for (int p = 0; p < 4; ++p) {
                int r = r0t + p * 32;
                const float4 v = *reinterpret_cast<const float4*>(
                    &x[(size_t)(row0 + r) * DDIM + d0 + g * 4]);
                As[r][g * 4 + 0] = v.x;
                As[r][g * 4 + 1] = v.y;
                As[r][g * 4 + 2] = v.z;
                As[r][g * 4 + 3] = v.w;
            }
        }
        // B tile: 32 d x 128 codes. float4 contiguous writes (conflict-free).
        {
            int c4 = tid & 31;
            int dd0 = tid >> 5;
#pragma unroll
            for (int p = 0; p < 4; ++p) {
                int dd = dd0 + p * 8;
                const float4 v = *reinterpret_cast<const float4*>(
                    &e[(size_t)(d0 + dd) * KCODES + c0 + c4 * 4]);
                *reinterpret_cast<float4*>(&Bs[dd][c4 * 4]) = v;
            }
        }
        __syncthreads();
#pragma unroll
        for (int dd = 0; dd < DK; ++dd) {
            // B fragments: two float4 at tx*4 and 64+tx*4 (bank-spread phases)
            float4 q0 = *reinterpret_cast<const float4*>(&Bs[dd][tx * 4]);
            float4 q1 = *reinterpret_cast<const float4*>(&Bs[dd][64 + tx * 4]);
            v2f b2[4];
            b2[0] = (v2f){q0.x, q0.y};
            b2[1] = (v2f){q0.z, q0.w};
            b2[2] = (v2f){q1.x, q1.y};
            b2[3] = (v2f){q1.z, q1.w};
#pragma unroll
            for (int i = 0; i < 8; ++i) {
                float av = As[ty * 8 + i][dd];  // 16-lane broadcast read
                v2f a2 = (v2f){av, av};
#pragma unroll
                for (int jp = 0; jp < 4; ++jp)
                    acc2[i][jp] =
                        __builtin_elementwise_fma(a2, b2[jp], acc2[i][jp]);
            }
        }
        __syncthreads();
    }

    // np dist: fl(fl(x2 + e2) - fl(2*sim)); first-min argmin, k ascending.
    // Per-thread codes in ascending order: tx*4..+3 then 64+tx*4..+3.
    float best[8];
    int bidx[8];
#pragma unroll
    for (int i = 0; i < 8; ++i) {
        best[i] = INFINITY;
        bidx[i] = 0x7fffffff;
    }
#pragma unroll
    for (int jp = 0; jp < 4; ++jp) {
#pragma unroll
        for (int h = 0; h < 2; ++h) {
            int k = (jp < 2) ? (c0 + tx * 4 + jp * 2 + h)
                             : (c0 + 64 + tx * 4 + (jp - 2) * 2 + h);
            float ek = e2g[k];
#pragma unroll
            for (int i = 0; i < 8; ++i) {
                float xr = x2g[row0 + ty * 8 + i];
                float u = __fadd_rn(xr, ek);
                float dct = __fsub_rn(u, __fmul_rn(2.0f, acc2[i][jp][h]));
                if (dct < best[i]) {  // strict <: first (lowest-k) min wins
                    best[i] = dct;
                    bidx[i] = k;
                }
            }
        }
    }
    // merge across the 16 tx lanes (xor masks stay inside 16-lane groups)
#pragma unroll
    for (int m = 1; m < 16; m <<= 1) {
#pragma unroll
        for (int i = 0; i < 8; ++i) {
            float od = __shfl_xor(best[i], m);
            int oi = __shfl_xor(bidx[i], m);
            if (od < best[i] || (od == best[i] && oi < bidx[i])) {
                best[i] = od;
                bidx[i] = oi;
            }
        }
    }
    if (tx == 0) {
#pragma unroll
        for (int i = 0; i < 8; ++i) {
            int row = row0 + ty * 8 + i;
            pdist[(size_t)ks * NROWS + row] = best[i];
            pidx[(size_t)ks * NROWS + row] = bidx[i];
        }
    }
}

// ------------- pick: merge splits (ks ascending == k ascending) -------------
__global__ __launch_bounds__(256) void vq_pick(const float* __restrict__ pdist,
                                               const int* __restrict__ pidx,
                                               int* __restrict__ idx) {
    int row = blockIdx.x * 256 + threadIdx.x;
    float gb = INFINITY;
    int gi = 0;
#pragma unroll
    for (int s = 0; s < KSPLIT; ++s) {
        float d = pdist[(size_t)s * NROWS + row];
        int k = pidx[(size_t)s * NROWS + row];
        if (d < gb) {
            gb = d;
            gi = k;
        }
    }
    idx[row] = gi;
}

// ------------- output: gather + fp32 STE out + per-block loss partial -------
__global__ __launch_bounds__(256) void vq_output(
    const float* __restrict__ x, const float* __restrict__ et,
    const int* __restrict__ idx, float* __restrict__ out,
    float* __restrict__ blockloss) {
    __shared__ int skb[64];
    __shared__ float red[256];
    const int rb = blockIdx.x;
    const int tid = threadIdx.x;
    if (tid < 64) skb[tid] = idx[rb * 64 + tid];
    __syncthreads();
    float lsum = 0.f;
    for (int r = 0; r < 64; ++r) {
        int row = rb * 64 + r;
        int k = skb[r];
        float xv = x[(size_t)row * DDIM + tid];
        float qv = et[(size_t)k * DDIM + tid];
        float diff = __fsub_rn(qv, xv);
        float qst = __fadd_rn(xv, diff);
        out[(size_t)row * DDIM + tid] = qst;
        lsum = fmaf(diff, diff, lsum);
    }
    red[tid] = lsum;
    __syncthreads();
    for (int s = 128; s > 0; s >>= 1) {
        if (tid < s) red[tid] += red[tid + s];
        __syncthreads();
    }
    if (tid == 0) blockloss[rb] = red[0];
}

// ---------------- deterministic loss reduce (fp32 scalar out) ---------------
__global__ __launch_bounds__(512) void vq_loss_reduce(
    const float* __restrict__ blockloss, float* __restrict__ out_loss) {
    __shared__ float red[512];
    int tid = threadIdx.x;
    red[tid] = blockloss[tid];
    __syncthreads();
    for (int s = 256; s > 0; s >>= 1) {
        if (tid < s) red[tid] += red[tid + s];
        __syncthreads();
    }
    if (tid == 0) {
        float m = __fmul_rn(red[0], 1.0f / (float)((size_t)NROWS * DDIM));
        out_loss[0] = __fadd_rn(__fmul_rn(0.25f, m), m);
    }
}

extern "C" void kernel_launch(void* const* d_in, const int* in_sizes, int n_in,
                              void* d_out, int out_size, void* d_ws,
                              size_t ws_size, hipStream_t stream) {
    const float* x = (const float*)d_in[0];  // [32768, 256] fp32
    const float* e = (const float*)d_in[1];  // [256, 1024]  fp32
    float* out = (float*)d_out;              // 8388608 qst + 1 loss, all fp32

    float* ws = (float*)d_ws;
    float* x2 = ws;                                     // 32768
    float* e2 = x2 + NROWS;                             // 1024
    float* et = e2 + KCODES;                            // 262144
    float* pdist = et + (size_t)KCODES * DDIM;          // 8*32768
    int* pidx = (int*)(pdist + (size_t)KSPLIT * NROWS); // 8*32768
    int* idx = pidx + (size_t)KSPLIT * NROWS;           // 32768
    float* blockloss = (float*)(idx + NROWS);           // 512

    vq_x2<<<NROWS / X2ROWS, 256, 0, stream>>>(x, x2);
    vq_e2<<<KCODES / 256, 256, 0, stream>>>(e, e2);
    vq_transpose<<<dim3(32, 8), 256, 0, stream>>>(e, et);
    vq_argmin_partial<<<dim3(NROWS / BM, KSPLIT), 256, 0, stream>>>(
        x, e, x2, e2, pdist, pidx);
    vq_pick<<<NROWS / 256, 256, 0, stream>>>(pdist, pidx, idx);
    vq_output<<<NROWS / 64, 256, 0, stream>>>(x, et, idx, out, blockloss);
    vq_loss_reduce<<<1, 512, 0, stream>>>(blockloss, out + (size_t)NROWS * DDIM);
}